// Round 1
// baseline (444.375 us; speedup 1.0000x reference)
//
#include <hip/hip_runtime.h>

// AdvectionLayer: bilinear warp of image [B=8,C=4,H=1024,W=1024] by flow [B,2,H,W].
// Coordinate math (reference, simplified):
//   vx = x + flow[b,0,y,x];  ix = vx * W/(W-1) - 0.5; clamp to [0, W-1]
//   vy = y + flow[b,1,y,x];  iy = vy * H/(H-1) - 0.5; clamp to [0, H-1]
// Then 2x2 bilinear gather with clamped indices (map_coordinates mode='nearest').

#define BB 8
#define CC 4
#define HH 1024
#define WW 1024

__global__ __launch_bounds__(256) void advect_kernel(
    const float* __restrict__ image,
    const float* __restrict__ flow,
    float* __restrict__ out)
{
    const int HW = HH * WW;
    int idx = blockIdx.x * blockDim.x + threadIdx.x;   // over B*H*W = 8M
    int x = idx & (WW - 1);
    int y = (idx >> 10) & (HH - 1);
    int b = idx >> 20;

    const float* fl = flow + (size_t)b * 2 * HW + (size_t)y * WW + x;
    float fx = fl[0];
    float fy = fl[HW];

    const float sx = (float)WW / (float)(WW - 1);
    const float sy = (float)HH / (float)(HH - 1);

    float ix = ((float)x + fx) * sx - 0.5f;
    float iy = ((float)y + fy) * sy - 0.5f;
    ix = fminf(fmaxf(ix, 0.0f), (float)(WW - 1));
    iy = fminf(fmaxf(iy, 0.0f), (float)(HH - 1));

    int x0 = (int)floorf(ix);
    int y0 = (int)floorf(iy);
    float wx = ix - (float)x0;
    float wy = iy - (float)y0;
    int x1 = min(x0 + 1, WW - 1);
    int y1 = min(y0 + 1, HH - 1);

    float w00 = (1.0f - wy) * (1.0f - wx);
    float w01 = (1.0f - wy) * wx;
    float w10 = wy * (1.0f - wx);
    float w11 = wy * wx;

    int o00 = y0 * WW + x0;
    int o01 = y0 * WW + x1;
    int o10 = y1 * WW + x0;
    int o11 = y1 * WW + x1;

    const float* imgb = image + (size_t)b * CC * HW;
    float* outb = out + (size_t)b * CC * HW;
    int op = y * WW + x;

#pragma unroll
    for (int c = 0; c < CC; ++c) {
        const float* p = imgb + (size_t)c * HW;
        float v = w00 * p[o00] + w01 * p[o01] + w10 * p[o10] + w11 * p[o11];
        outb[(size_t)c * HW + op] = v;
    }
}

extern "C" void kernel_launch(void* const* d_in, const int* in_sizes, int n_in,
                              void* d_out, int out_size, void* d_ws, size_t ws_size,
                              hipStream_t stream) {
    const float* image = (const float*)d_in[0];
    const float* flow  = (const float*)d_in[1];
    float* out = (float*)d_out;

    const int total = BB * HH * WW;           // 8M threads, one per (b,y,x)
    const int block = 256;
    const int grid = (total + block - 1) / block;
    advect_kernel<<<grid, block, 0, stream>>>(image, flow, out);
}

// Round 2
// 381.461 us; speedup vs baseline: 1.1649x; 1.1649x over previous
//
#include <hip/hip_runtime.h>

// AdvectionLayer: bilinear warp of image [B=8,C=4,H=1024,W=1024] by flow [B,2,H,W].
//
// Round-1 analysis: single-kernel gather was TA/coalescing-limited (1.18 TB/s,
// VALUBusy 8%): 16 gather insts/thread, each touching ~64 cache lines/wave.
// Round-2: transpose image to channel-interleaved [B,H,W,C] (float4) in d_ws,
// then gather with ONE float4 load per tap (4 divergent loads/thread total).

#define BB 8
#define CC 4
#define HH 1024
#define WW 1024
#define HW (HH * WW)

__global__ __launch_bounds__(256) void interleave_kernel(
    const float* __restrict__ image,
    float4* __restrict__ ws)
{
    int idx = blockIdx.x * blockDim.x + threadIdx.x;   // over B*H*W
    int b = idx >> 20;
    int p = idx & (HW - 1);
    const float* base = image + (size_t)b * CC * HW + p;
    float4 v;
    v.x = base[0];
    v.y = base[HW];
    v.z = base[2 * HW];
    v.w = base[3 * HW];
    ws[idx] = v;
}

__global__ __launch_bounds__(256) void advect_gather_kernel(
    const float4* __restrict__ ws,
    const float* __restrict__ flow,
    float* __restrict__ out)
{
    int idx = blockIdx.x * blockDim.x + threadIdx.x;   // over B*H*W
    int x = idx & (WW - 1);
    int y = (idx >> 10) & (HH - 1);
    int b = idx >> 20;

    const float* fl = flow + (size_t)b * 2 * HW + (size_t)y * WW + x;
    float fx = fl[0];
    float fy = fl[HW];

    const float sx = (float)WW / (float)(WW - 1);
    const float sy = (float)HH / (float)(HH - 1);

    float ix = ((float)x + fx) * sx - 0.5f;
    float iy = ((float)y + fy) * sy - 0.5f;
    ix = fminf(fmaxf(ix, 0.0f), (float)(WW - 1));
    iy = fminf(fmaxf(iy, 0.0f), (float)(HH - 1));

    int x0 = (int)floorf(ix);
    int y0 = (int)floorf(iy);
    float wx = ix - (float)x0;
    float wy = iy - (float)y0;
    int x1 = min(x0 + 1, WW - 1);
    int y1 = min(y0 + 1, HH - 1);

    const float4* wsb = ws + (size_t)b * HW;
    float4 t00 = wsb[y0 * WW + x0];
    float4 t01 = wsb[y0 * WW + x1];
    float4 t10 = wsb[y1 * WW + x0];
    float4 t11 = wsb[y1 * WW + x1];

    float w00 = (1.0f - wy) * (1.0f - wx);
    float w01 = (1.0f - wy) * wx;
    float w10 = wy * (1.0f - wx);
    float w11 = wy * wx;

    float r0 = w00 * t00.x + w01 * t01.x + w10 * t10.x + w11 * t11.x;
    float r1 = w00 * t00.y + w01 * t01.y + w10 * t10.y + w11 * t11.y;
    float r2 = w00 * t00.z + w01 * t01.z + w10 * t10.z + w11 * t11.z;
    float r3 = w00 * t00.w + w01 * t01.w + w10 * t10.w + w11 * t11.w;

    float* outb = out + (size_t)b * CC * HW + (size_t)y * WW + x;
    outb[0] = r0;
    outb[HW] = r1;
    outb[2 * HW] = r2;
    outb[3 * HW] = r3;
}

// Fallback (round-1 kernel) if ws is too small for the interleaved copy.
__global__ __launch_bounds__(256) void advect_fallback_kernel(
    const float* __restrict__ image,
    const float* __restrict__ flow,
    float* __restrict__ out)
{
    int idx = blockIdx.x * blockDim.x + threadIdx.x;
    int x = idx & (WW - 1);
    int y = (idx >> 10) & (HH - 1);
    int b = idx >> 20;

    const float* fl = flow + (size_t)b * 2 * HW + (size_t)y * WW + x;
    float fx = fl[0];
    float fy = fl[HW];

    const float sx = (float)WW / (float)(WW - 1);
    const float sy = (float)HH / (float)(HH - 1);

    float ix = ((float)x + fx) * sx - 0.5f;
    float iy = ((float)y + fy) * sy - 0.5f;
    ix = fminf(fmaxf(ix, 0.0f), (float)(WW - 1));
    iy = fminf(fmaxf(iy, 0.0f), (float)(HH - 1));

    int x0 = (int)floorf(ix);
    int y0 = (int)floorf(iy);
    float wx = ix - (float)x0;
    float wy = iy - (float)y0;
    int x1 = min(x0 + 1, WW - 1);
    int y1 = min(y0 + 1, HH - 1);

    float w00 = (1.0f - wy) * (1.0f - wx);
    float w01 = (1.0f - wy) * wx;
    float w10 = wy * (1.0f - wx);
    float w11 = wy * wx;

    int o00 = y0 * WW + x0;
    int o01 = y0 * WW + x1;
    int o10 = y1 * WW + x0;
    int o11 = y1 * WW + x1;

    const float* imgb = image + (size_t)b * CC * HW;
    float* outb = out + (size_t)b * CC * HW;
    int op = y * WW + x;

#pragma unroll
    for (int c = 0; c < CC; ++c) {
        const float* p = imgb + (size_t)c * HW;
        float v = w00 * p[o00] + w01 * p[o01] + w10 * p[o10] + w11 * p[o11];
        outb[(size_t)c * HW + op] = v;
    }
}

extern "C" void kernel_launch(void* const* d_in, const int* in_sizes, int n_in,
                              void* d_out, int out_size, void* d_ws, size_t ws_size,
                              hipStream_t stream) {
    const float* image = (const float*)d_in[0];
    const float* flow  = (const float*)d_in[1];
    float* out = (float*)d_out;

    const int total = BB * HH * WW;            // 8M threads, one per (b,y,x)
    const int block = 256;
    const int grid = (total + block - 1) / block;

    const size_t need = (size_t)BB * HW * CC * sizeof(float);  // 128 MiB interleaved copy
    if (ws_size >= need) {
        float4* ws = (float4*)d_ws;
        interleave_kernel<<<grid, block, 0, stream>>>(image, ws);
        advect_gather_kernel<<<grid, block, 0, stream>>>(ws, flow, out);
    } else {
        advect_fallback_kernel<<<grid, block, 0, stream>>>(image, flow, out);
    }
}

// Round 3
// 309.407 us; speedup vs baseline: 1.4362x; 1.2329x over previous
//
#include <hip/hip_runtime.h>

// AdvectionLayer: bilinear warp of image [B=8,C=4,H=1024,W=1024] by flow [B,2,H,W].
//
// R1: planar gather, TA/line-fill limited, 274 us.
// R2: fp32 channel-interleaved ws, 4 float4 gathers -> 145 us, still line-fill limited.
// R3: fp16 channel-interleaved ws (8 B/pixel: 128B line = 16 pixels, halves line
//     fills), 2x 16B row-pair loads per thread (covers both x taps), 32x8 2D
//     block tiles so block gather footprint (~34 KB) fits L1.

#define BB 8
#define CC 4
#define HH 1024
#define WW 1024
#define HW (HH * WW)

typedef _Float16 h4 __attribute__((ext_vector_type(4)));  // one pixel, 8 B
typedef _Float16 h8 __attribute__((ext_vector_type(8)));  // two adjacent pixels, 16 B

__global__ __launch_bounds__(256) void interleave_fp16_kernel(
    const float* __restrict__ image,
    h4* __restrict__ ws)
{
    int idx = blockIdx.x * blockDim.x + threadIdx.x;   // over B*H*W
    int b = idx >> 20;
    int p = idx & (HW - 1);
    const float* base = image + (size_t)b * CC * HW + p;
    h4 v;
    v.x = (_Float16)base[0];
    v.y = (_Float16)base[HW];
    v.z = (_Float16)base[2 * HW];
    v.w = (_Float16)base[3 * HW];
    ws[idx] = v;
}

__global__ __launch_bounds__(256) void advect_gather_fp16_kernel(
    const _Float16* __restrict__ ws,
    const float* __restrict__ flow,
    float* __restrict__ out)
{
    // block covers a 32x8 output tile; lanes 32 wide x 2 tall per wave
    int tx = threadIdx.x & 31;
    int ty = threadIdx.x >> 5;
    int x = (blockIdx.x << 5) + tx;
    int y = (blockIdx.y << 3) + ty;
    int b = blockIdx.z;

    const float* fl = flow + (size_t)b * 2 * HW + (size_t)y * WW + x;
    float fx = fl[0];
    float fy = fl[HW];

    const float sx = (float)WW / (float)(WW - 1);
    const float sy = (float)HH / (float)(HH - 1);

    float ix = ((float)x + fx) * sx - 0.5f;
    float iy = ((float)y + fy) * sy - 0.5f;
    ix = fminf(fmaxf(ix, 0.0f), (float)(WW - 1));
    iy = fminf(fmaxf(iy, 0.0f), (float)(HH - 1));

    // xl in [0, W-2], wx = ix - xl in [0,1]; border clamp is baked into the lerp
    int xl = min((int)ix, WW - 2);
    int yl = min((int)iy, HH - 2);
    float wx = ix - (float)xl;
    float wy = iy - (float)yl;

    const _Float16* wsb = ws + (size_t)b * HW * 4;
    const _Float16* p0 = wsb + ((size_t)yl * WW + xl) * 4;        // row yl, pixels xl, xl+1
    const _Float16* p1 = p0 + (size_t)WW * 4;                     // row yl+1

    h8 t0, t1;
    __builtin_memcpy(&t0, p0, 16);
    __builtin_memcpy(&t1, p1, 16);

    float u0 = 1.0f - wx;
    float v0 = 1.0f - wy;

    float* outb = out + (size_t)b * CC * HW + (size_t)y * WW + x;
#pragma unroll
    for (int c = 0; c < CC; ++c) {
        float top = u0 * (float)t0[c] + wx * (float)t0[4 + c];
        float bot = u0 * (float)t1[c] + wx * (float)t1[4 + c];
        outb[(size_t)c * HW] = v0 * top + wy * bot;
    }
}

// Fallback (round-1 kernel) if ws is too small.
__global__ __launch_bounds__(256) void advect_fallback_kernel(
    const float* __restrict__ image,
    const float* __restrict__ flow,
    float* __restrict__ out)
{
    int idx = blockIdx.x * blockDim.x + threadIdx.x;
    int x = idx & (WW - 1);
    int y = (idx >> 10) & (HH - 1);
    int b = idx >> 20;

    const float* fl = flow + (size_t)b * 2 * HW + (size_t)y * WW + x;
    float fx = fl[0];
    float fy = fl[HW];

    const float sx = (float)WW / (float)(WW - 1);
    const float sy = (float)HH / (float)(HH - 1);

    float ix = ((float)x + fx) * sx - 0.5f;
    float iy = ((float)y + fy) * sy - 0.5f;
    ix = fminf(fmaxf(ix, 0.0f), (float)(WW - 1));
    iy = fminf(fmaxf(iy, 0.0f), (float)(HH - 1));

    int xl = min((int)ix, WW - 2);
    int yl = min((int)iy, HH - 2);
    float wx = ix - (float)xl;
    float wy = iy - (float)yl;

    float w00 = (1.0f - wy) * (1.0f - wx);
    float w01 = (1.0f - wy) * wx;
    float w10 = wy * (1.0f - wx);
    float w11 = wy * wx;

    int o00 = yl * WW + xl;
    int o01 = o00 + 1;
    int o10 = o00 + WW;
    int o11 = o10 + 1;

    const float* imgb = image + (size_t)b * CC * HW;
    float* outb = out + (size_t)b * CC * HW;
    int op = y * WW + x;

#pragma unroll
    for (int c = 0; c < CC; ++c) {
        const float* p = imgb + (size_t)c * HW;
        float v = w00 * p[o00] + w01 * p[o01] + w10 * p[o10] + w11 * p[o11];
        outb[(size_t)c * HW + op] = v;
    }
}

extern "C" void kernel_launch(void* const* d_in, const int* in_sizes, int n_in,
                              void* d_out, int out_size, void* d_ws, size_t ws_size,
                              hipStream_t stream) {
    const float* image = (const float*)d_in[0];
    const float* flow  = (const float*)d_in[1];
    float* out = (float*)d_out;

    const size_t need = (size_t)BB * HW * CC * sizeof(_Float16);  // 64 MiB fp16 interleaved
    if (ws_size >= need) {
        const int total = BB * HH * WW;
        interleave_fp16_kernel<<<total / 256, 256, 0, stream>>>(image, (h4*)d_ws);
        dim3 grid(WW / 32, HH / 8, BB);
        advect_gather_fp16_kernel<<<grid, 256, 0, stream>>>((const _Float16*)d_ws, flow, out);
    } else {
        const int total = BB * HH * WW;
        advect_fallback_kernel<<<(total + 255) / 256, 256, 0, stream>>>(image, flow, out);
    }
}